// Round 18
// baseline (73.604 us; speedup 1.0000x reference)
//
#include <hip/hip_runtime.h>

typedef float f32x4 __attribute__((ext_vector_type(4)));
typedef float f32x16 __attribute__((ext_vector_type(16)));
typedef unsigned int u32x4 __attribute__((ext_vector_type(4)));
typedef __bf16 bf16x8 __attribute__((ext_vector_type(8)));
typedef unsigned short ushort_t;

#define NEG2 (-144269.5f)   /* -1e5 * log2(e) */
#define SCLQ (0.18033688f)  /* 0.125 * log2(e) */

constexpr int Ss = 2048, Ee = 1024, Hh = 64;

static __device__ __forceinline__ ushort_t f2bfu(float f) {
  return __builtin_bit_cast(ushort_t, (__bf16)f);
}
static __device__ __forceinline__ f32x4 mfma16(bf16x8 a, bf16x8 b, f32x4 c) {
  return __builtin_amdgcn_mfma_f32_16x16x32_bf16(a, b, c, 0, 0, 0);
}
static __device__ __forceinline__ f32x16 mfma32(bf16x8 a, bf16x8 b, f32x16 c) {
  return __builtin_amdgcn_mfma_f32_32x32x16_bf16(a, b, c, 0, 0, 0);
}
static __device__ __forceinline__ unsigned cvtpk(float a, float b) {
  unsigned r;
  asm("v_cvt_pk_bf16_f32 %0, %1, %2" : "=v"(r) : "v"(a), "v"(b));
  return r;
}
// NOTE: only call with a,b holding DIFFERENT values (R3 bug).
static __device__ __forceinline__ void swap32(unsigned& a, unsigned& b) {
  asm("v_permlane32_swap_b32 %0, %1" : "+v"(a), "+v"(b));
}

// ============ Fragment-major layouts (16B-unit indices unless noted) ============
// Q/K: F(b,t32,c,hi,lo,j) = ((((b*64+t32)*4+c)*2+hi)*32+lo)*8+j   [ushort idx]
// V:   G(b,s16,dt,hi,lo,j) = ((((b*128+s16)*2+dt)*2+hi)*32+lo)*8+j
// Wf (weights, fragment-major, read DIRECT from L2 — no LDS):
//   16B-unit (s, T, ks, c, g) = (((s*12 + T)*2 + ks)*16 + c)*4 + g
//   s = k-step (64 wide), T = col-tile (rr>>4, rr = m*64+h), c = rr&15,
//   ks = k-half (32), g = k-oct (8). Lane (c,g) of a wave -> unit c*4+g:
//   bijection over 0..63 -> ONE coalesced 1KB b128 load per (s,T,ks).
// R16 DIAGNOSIS: proj ~34us (spill) -> R17 ~23us (LDS-pipe: 14 ds_read_b128 +
// barrier drain per step). R18: W direct-from-L2, A staged once, 0 loop barriers.

// ---------------- weight transpose + bf16 convert -> Wf ----------------
__global__ __launch_bounds__(256) void k_wtrans(const float* __restrict__ Wq,
                                                const float* __restrict__ Wk,
                                                const float* __restrict__ Wv,
                                                ushort_t* __restrict__ Wf) {
  __shared__ float tile[64][65];
  const float* W = (blockIdx.y == 0) ? Wq : (blockIdx.y == 1 ? Wk : Wv);
  int kt = blockIdx.x, t = threadIdx.x;
  int r = t >> 2, cq = t & 3;
  const float* src = W + (kt * 64 + r) * Hh + cq * 16;
#pragma unroll
  for (int j = 0; j < 16; j += 4) {
    float4 v = *reinterpret_cast<const float4*>(src + j);
    tile[r][cq * 16 + j + 0] = v.x;
    tile[r][cq * 16 + j + 1] = v.y;
    tile[r][cq * 16 + j + 2] = v.z;
    tile[r][cq * 16 + j + 3] = v.w;
  }
  __syncthreads();
  int n = t >> 2, kq = t & 3;
  int rr = blockIdx.y * 64 + n;  // output row 0..191 (m*64 + h)
  ushort_t ob[16];
#pragma unroll
  for (int j = 0; j < 16; ++j) ob[j] = f2bfu(tile[kq * 16 + j][n]);
  int T = rr >> 4, c = rr & 15;
#pragma unroll
  for (int j8 = 0; j8 < 2; ++j8) {
    int ks = kq >> 1, g = (kq & 1) * 2 + j8;  // k = kt*64 + ks*32 + g*8
    size_t unit = ((((size_t)kt * 12 + T) * 2 + ks) * 16 + c) * 4 + g;
    *reinterpret_cast<uint4*>(Wf + unit * 8) = reinterpret_cast<uint4*>(ob)[j8];
  }
}

// ---------------- fused QKV projection v4: W direct-from-L2, barrier-free K-loop ----
// 512 blocks x 256 thr (4 waves; wm=w>>1 row-half, wn=w&1 col-half). A (32 rows
// x 1024 k) staged ONCE into LDS in fragment layout (64 KB, bijective lane map,
// conflict-free), ONE barrier; then 16 K-steps with NO barriers: per step 12
// coalesced b128 W loads from L2 + 2 ds_read + 12 mfma16. LDS-pipe per step
// drops 14 reads -> 2 (R17 diagnosis). 2 blocks/CU: one stages (HBM) while the
// other computes (L2). Epilogue scatters into fragment-major q/k/v.
__global__ __launch_bounds__(256, 2) void k_proj(const float* __restrict__ hs,
                                                 const float* __restrict__ bq,
                                                 const float* __restrict__ bk,
                                                 const float* __restrict__ bv,
                                                 const ushort_t* __restrict__ Wf,
                                                 const int* __restrict__ am,
                                                 ushort_t* __restrict__ qf_,
                                                 ushort_t* __restrict__ kf_,
                                                 ushort_t* __restrict__ vf_,
                                                 float* __restrict__ pen) {
  // A_lds 16B-unit (s, ks, wm, c, g) = (((s*2+ks)*2+wm)*16+c)*4 + g  -> 64 KB
  __shared__ __align__(16) ushort_t A[16 * 2 * 2 * 16 * 4 * 8];

  int t = threadIdx.x, w = t >> 6, l = t & 63, g = l >> 4, c = l & 15;
  int wm = w >> 1, wn = w & 1;
  int row0 = blockIdx.x * 32;

  // ---- stage A once: thread (ar = t>>3, ach = t&7), 16 passes over k ----
  {
    int ar = t >> 3, ach = t & 7;
    int aks = ach >> 2, ag = ach & 3, awm = ar >> 4, ac = ar & 15;
    const float* agp = hs + (size_t)(row0 + ar) * Ee + ach * 8;
#pragma unroll 4
    for (int ki = 0; ki < 16; ++ki) {
      float4 f0 = *reinterpret_cast<const float4*>(agp + ki * 64);
      float4 f1 = *reinterpret_cast<const float4*>(agp + ki * 64 + 4);
      bf16x8 av;
      av[0] = (__bf16)f0.x; av[1] = (__bf16)f0.y; av[2] = (__bf16)f0.z; av[3] = (__bf16)f0.w;
      av[4] = (__bf16)f1.x; av[5] = (__bf16)f1.y; av[6] = (__bf16)f1.z; av[7] = (__bf16)f1.w;
      int unit = (((ki * 2 + aks) * 2 + awm) * 16 + ac) * 4 + ag;
      *reinterpret_cast<bf16x8*>(&A[unit * 8]) = av;
    }
  }
  __syncthreads();  // the ONLY barrier

  f32x4 acc[6];
#pragma unroll
  for (int nt = 0; nt < 6; ++nt) acc[nt] = f32x4{0.f, 0.f, 0.f, 0.f};

  const int lane_u = c * 4 + g;  // per-lane 16B-unit offset within a frag row

  for (int s = 0; s < 16; ++s) {
    bf16x8 af0 = *reinterpret_cast<const bf16x8*>(&A[((((s * 2 + 0) * 2 + wm) * 16 + c) * 4 + g) * 8]);
    bf16x8 af1 = *reinterpret_cast<const bf16x8*>(&A[((((s * 2 + 1) * 2 + wm) * 16 + c) * 4 + g) * 8]);
#pragma unroll
    for (int nt = 0; nt < 6; ++nt) {
      int T = wn * 6 + nt;
      const ushort_t* wp = Wf + ((size_t)(s * 12 + T) * 2 * 64 + lane_u) * 8;
      bf16x8 b0 = *reinterpret_cast<const bf16x8*>(wp);            // ks=0
      bf16x8 b1 = *reinterpret_cast<const bf16x8*>(wp + 64 * 8);   // ks=1
      acc[nt] = mfma16(af0, b0, acc[nt]);
      acc[nt] = mfma16(af1, b1, acc[nt]);
    }
  }

  // epilogue: scatter into fragment-major layouts
#pragma unroll
  for (int nt = 0; nt < 6; ++nt) {
    int T = wn * 6 + nt;
    int m = T >> 2;
    int h = (T & 3) * 16 + c;
    const float* bias = (m == 0) ? bq : ((m == 1) ? bk : bv);
    float bb = bias[h];
    int cc = h >> 4, hh = (h >> 3) & 1, jj = h & 7;
    int dt = h >> 5, dl = h & 31;
#pragma unroll
    for (int i = 0; i < 4; ++i) {
      int row = row0 + wm * 16 + g * 4 + i;
      float val = acc[nt][i] + bb;
      int bi = row >> 11, rl = row & 2047;
      if (m == 0) {
        size_t a = ((((size_t)(bi * 64 + (rl >> 5)) * 4 + cc) * 2 + hh) * 32 + (rl & 31)) * 8 + jj;
        qf_[a] = f2bfu(val * SCLQ);
      } else if (m == 1) {
        size_t a = ((((size_t)(bi * 64 + (rl >> 5)) * 4 + cc) * 2 + hh) * 32 + (rl & 31)) * 8 + jj;
        kf_[a] = f2bfu(val);
      } else {
        int s16 = rl >> 4, vh = (rl >> 3) & 1, vj = rl & 7;
        size_t a = ((((size_t)(bi * 128 + s16) * 2 + dt) * 2 + vh) * 32 + dl) * 8 + vj;
        vf_[a] = f2bfu(val);
      }
    }
  }

  if (t < 32) {
    int grow = row0 + t;
    int bi = grow >> 11, s2 = grow & 2047;
    int mv = am[grow];
    pen[((size_t)bi * 2 + 0) * Ss + s2] = mv ? 0.f : NEG2;
    pen[((size_t)bi * 2 + 1) * Ss + s2] = mv ? NEG2 : 0.f;
  }
}

// ---------------- fused masked flash attention (R13, measured ~21.6us) ----
// grid 1024: b = bid&7 (batch-per-XCD), qt = (bid>>3)&63, kh = bid>>9 (k-split).
// 256 thr / 4 waves; wave w owns keys [kh*1024 + w*256, +256). Every K/V/Q
// fragment load is ONE coalesced b128 (L2-resident); no LDS staging, no loop
// barriers; launch_bounds(256,3) (cap ~170; (256,4) spills — R12).
// Fixed m=0 softmax -> k-split partials are plain sums; k_fin combines.
__global__ __launch_bounds__(256, 3) void k_attn(const ushort_t* __restrict__ qs,
                                                 const ushort_t* __restrict__ km,
                                                 const ushort_t* __restrict__ vm,
                                                 const int* __restrict__ am,
                                                 const float* __restrict__ pen,
                                                 float* __restrict__ opart,
                                                 float* __restrict__ lpart) {
  __shared__ float obuf[4][32][68];
  __shared__ float lls[4][32];

  int t = threadIdx.x, w = t >> 6, l = t & 63, lo = l & 31, hi = l >> 5;
  int bid = blockIdx.x;
  int b = bid & 7, qt = (bid >> 3) & 63, kh = bid >> 9;
  int q0 = qt * 32;

  const size_t laneoff = (size_t)hi * 256 + lo * 8;

  const ushort_t* qbase = qs + (size_t)(b * 64 + qt) * 2048 + laneoff;
  bf16x8 qf[4];
#pragma unroll
  for (int c = 0; c < 4; ++c)
    qf[c] = *reinterpret_cast<const bf16x8*>(qbase + (size_t)c * 512);

  int mq = am[b * Ss + q0 + lo];
  float negq = mq ? NEG2 : 0.f;
  const float* psel = pen + ((size_t)b * 2 + (mq ? 0 : 1)) * Ss;

  float ll = 0.f;
  f32x16 o0 = {0.f, 0.f, 0.f, 0.f, 0.f, 0.f, 0.f, 0.f, 0.f, 0.f, 0.f, 0.f, 0.f, 0.f, 0.f, 0.f};
  f32x16 o1 = o0;
  const f32x16 z16 = o0;

  const int kvbeg = kh * 1024 + w * 256;
  const ushort_t* kb = km + (size_t)b * 131072 + laneoff;
  const ushort_t* vb = vm + (size_t)b * 131072 + laneoff;

  for (int it = 0; it < 8; ++it) {
    const int kv0 = kvbeg + it * 32;
    const int kt32 = kv0 >> 5, s16 = kv0 >> 4;

    const ushort_t* kfp = kb + (size_t)kt32 * 2048;
    bf16x8 kf0 = *reinterpret_cast<const bf16x8*>(kfp);
    bf16x8 kf1 = *reinterpret_cast<const bf16x8*>(kfp + 512);
    bf16x8 kf2 = *reinterpret_cast<const bf16x8*>(kfp + 1024);
    bf16x8 kf3 = *reinterpret_cast<const bf16x8*>(kfp + 1536);
    const ushort_t* vfp = vb + (size_t)s16 * 1024;
    bf16x8 vf00 = *reinterpret_cast<const bf16x8*>(vfp);
    bf16x8 vf01 = *reinterpret_cast<const bf16x8*>(vfp + 512);
    bf16x8 vf10 = *reinterpret_cast<const bf16x8*>(vfp + 1024);
    bf16x8 vf11 = *reinterpret_cast<const bf16x8*>(vfp + 1536);

    f32x4 pv[4];
#pragma unroll
    for (int j = 0; j < 4; ++j)
      pv[j] = *reinterpret_cast<const f32x4*>(psel + kv0 + j * 8 + hi * 4);

    f32x16 sc = mfma32(kf0, qf[0], z16);
    sc = mfma32(kf1, qf[1], sc);
    sc = mfma32(kf2, qf[2], sc);
    sc = mfma32(kf3, qf[3], sc);

    if (kv0 == q0) {
#pragma unroll
      for (int r = 0; r < 16; ++r) {
        int kr = (r & 3) + 8 * (r >> 2) + 4 * hi;
        sc[r] += pv[r >> 2][r & 3] + ((kr > lo) ? negq : 0.f);
      }
    } else {
      float addt = (kv0 > q0) ? negq : 0.f;
#pragma unroll
      for (int r = 0; r < 16; ++r) sc[r] += pv[r >> 2][r & 3] + addt;
    }

    float p[16], ts = 0.f;
#pragma unroll
    for (int r = 0; r < 16; ++r) {
      p[r] = __builtin_amdgcn_exp2f(sc[r]);
      ts += p[r];
    }
    ll += ts;

    unsigned x0 = cvtpk(p[0], p[1]), y0 = cvtpk(p[2], p[3]);
    unsigned z0 = cvtpk(p[4], p[5]), w0 = cvtpk(p[6], p[7]);
    swap32(x0, z0);
    swap32(y0, w0);
    unsigned x1 = cvtpk(p[8], p[9]), y1 = cvtpk(p[10], p[11]);
    unsigned z1 = cvtpk(p[12], p[13]), w1 = cvtpk(p[14], p[15]);
    swap32(x1, z1);
    swap32(y1, w1);
    bf16x8 pa0 = __builtin_bit_cast(bf16x8, u32x4{x0, y0, z0, w0});
    bf16x8 pa1 = __builtin_bit_cast(bf16x8, u32x4{x1, y1, z1, w1});

    o0 = mfma32(pa0, vf00, o0);
    o0 = mfma32(pa1, vf10, o0);
    o1 = mfma32(pa0, vf01, o1);
    o1 = mfma32(pa1, vf11, o1);
  }

  ll += __shfl_xor(ll, 32);

#pragma unroll
  for (int r = 0; r < 16; ++r) {
    int qrow = (r & 3) + 8 * (r >> 2) + 4 * hi;
    obuf[w][qrow][lo] = o0[r];
    obuf[w][qrow][32 + lo] = o1[r];
  }
  if (hi == 0) lls[w][lo] = ll;
  __syncthreads();

  int qr = t >> 3, dg = t & 7;
  float lg = lls[0][qr] + lls[1][qr] + lls[2][qr] + lls[3][qr];
  float a8[8] = {0.f, 0.f, 0.f, 0.f, 0.f, 0.f, 0.f, 0.f};
#pragma unroll
  for (int ww = 0; ww < 4; ++ww) {
    float4 c0 = *reinterpret_cast<const float4*>(&obuf[ww][qr][dg * 8]);
    float4 c1 = *reinterpret_cast<const float4*>(&obuf[ww][qr][dg * 8 + 4]);
    a8[0] += c0.x; a8[1] += c0.y; a8[2] += c0.z; a8[3] += c0.w;
    a8[4] += c1.x; a8[5] += c1.y; a8[6] += c1.z; a8[7] += c1.w;
  }
  float* op = opart + (((size_t)kh * 8 + b) * Ss + q0 + qr) * 64 + dg * 8;
  float4 r0v = {a8[0], a8[1], a8[2], a8[3]};
  float4 r1v = {a8[4], a8[5], a8[6], a8[7]};
  *reinterpret_cast<float4*>(op) = r0v;
  *reinterpret_cast<float4*>(op + 4) = r1v;
  if (dg == 0) lpart[((size_t)kh * 8 + b) * Ss + q0 + qr] = lg;
}

// ---------------- finalize: out = (opart0 + opart1) / (l0 + l1) ----------------
__global__ __launch_bounds__(256) void k_fin(const float* __restrict__ op,
                                             const float* __restrict__ lp,
                                             float* __restrict__ out) {
  int gi = blockIdx.x * 256 + threadIdx.x;
  int row = gi >> 4;
  float lsum = lp[row] + lp[row + 16384];
  f32x4 a = reinterpret_cast<const f32x4*>(op)[gi];
  f32x4 b = reinterpret_cast<const f32x4*>(op)[gi + 262144];
  float inv = 1.f / lsum;
  f32x4 r = (a + b) * inv;
  reinterpret_cast<f32x4*>(out)[gi] = r;
}

extern "C" void kernel_launch(void* const* d_in, const int* in_sizes, int n_in,
                              void* d_out, int out_size, void* d_ws, size_t ws_size,
                              hipStream_t stream) {
  const float* hs = (const float*)d_in[0];
  const int* am = (const int*)d_in[1];
  const float* Wq = (const float*)d_in[2];
  const float* bq = (const float*)d_in[3];
  const float* Wk = (const float*)d_in[4];
  const float* bk = (const float*)d_in[5];
  const float* Wv = (const float*)d_in[6];
  const float* bv = (const float*)d_in[7];
  float* out = (float*)d_out;

  char* ws = (char*)d_ws;
  ushort_t* qsp = (ushort_t*)(ws + 0);                  // 2 MB: Q fragment-major, scaled
  ushort_t* kp = (ushort_t*)(ws + (2u << 20));          // 2 MB: K fragment-major
  ushort_t* vtp = (ushort_t*)(ws + (4u << 20));         // 2 MB: V fragment-major
  ushort_t* wtp = (ushort_t*)(ws + (6u << 20));         // 384 KB: Wf fragment-major
  float* penp = (float*)(ws + (6u << 20) + (512u << 10));  // 128 KB: [B][2][S] f32
  float* opart = (float*)(ws + (8u << 20));             // 8 MB: [2][B][S][64] f32
  float* lpart = (float*)(ws + (16u << 20));            // 128 KB: [2][B][S] f32

  k_wtrans<<<dim3(16, 3), 256, 0, stream>>>(Wq, Wk, Wv, wtp);
  k_proj<<<dim3(512), 256, 0, stream>>>(hs, bq, bk, bv, wtp, am, qsp, kp, vtp, penp);
  k_attn<<<dim3(1024), 256, 0, stream>>>(qsp, kp, vtp, am, penp, opart, lpart);
  k_fin<<<dim3(1024), 256, 0, stream>>>(opart, lpart, out);
}

// Round 19
// 54.392 us; speedup vs baseline: 1.3532x; 1.3532x over previous
//
#include <hip/hip_runtime.h>

typedef float f32x4 __attribute__((ext_vector_type(4)));
typedef float f32x16 __attribute__((ext_vector_type(16)));
typedef unsigned int u32x4 __attribute__((ext_vector_type(4)));
typedef __bf16 bf16x8 __attribute__((ext_vector_type(8)));
typedef unsigned short ushort_t;

#define NEG2 (-144269.5f)   /* -1e5 * log2(e) */
#define SCLQ (0.18033688f)  /* 0.125 * log2(e) */

constexpr int Ss = 2048, Ee = 1024, Hh = 64;

static __device__ __forceinline__ ushort_t f2bfu(float f) {
  return __builtin_bit_cast(ushort_t, (__bf16)f);
}
static __device__ __forceinline__ f32x4 mfma16(bf16x8 a, bf16x8 b, f32x4 c) {
  return __builtin_amdgcn_mfma_f32_16x16x32_bf16(a, b, c, 0, 0, 0);
}
static __device__ __forceinline__ f32x16 mfma32(bf16x8 a, bf16x8 b, f32x16 c) {
  return __builtin_amdgcn_mfma_f32_32x32x16_bf16(a, b, c, 0, 0, 0);
}
static __device__ __forceinline__ unsigned cvtpk(float a, float b) {
  unsigned r;
  asm("v_cvt_pk_bf16_f32 %0, %1, %2" : "=v"(r) : "v"(a), "v"(b));
  return r;
}
// NOTE: only call with a,b holding DIFFERENT values (R3 bug).
static __device__ __forceinline__ void swap32(unsigned& a, unsigned& b) {
  asm("v_permlane32_swap_b32 %0, %1" : "+v"(a), "+v"(b));
}
// async global->LDS, 16B per lane; LDS dest = uniform base + lane*16 (m104)
static __device__ __forceinline__ void gload_lds16(const void* g, void* l) {
  __builtin_amdgcn_global_load_lds(
      (const __attribute__((address_space(1))) unsigned int*)g,
      (__attribute__((address_space(3))) unsigned int*)l, 16, 0, 0);
}

// ============ Fragment-major layouts (ushort element offsets) ============
// Q/K: F(b,t32,c,hi,lo,j) = ((((b*64+t32)*4+c)*2+hi)*32+lo)*8+j
// V:   G(b,s16,dt,hi,lo,j) = ((((b*128+s16)*2+dt)*2+hi)*32+lo)*8+j
// Wsw: off = (s*192 + r)*64 + ((c16 ^ (r&7)) * 8)
// HISTORY: R16 diag: proj 34us = (512,4) spill (VGPR 64, WRITE 67MB).
// R17: (256,2) 512-block shape -> no spill but 8 waves/CU -> ~23us.
// R18: W-direct-from-L2 -> latency-bound regression (~45us), reverted.
// R19: R15 shape (256 blocks x 512 thr, async-GLW 1-barrier pipeline) with
// (512,2): no spill AND 16 waves/CU.

// ---------------- weight transpose + bf16 convert -> Wsw ----------------
__global__ __launch_bounds__(256) void k_wtrans(const float* __restrict__ Wq,
                                                const float* __restrict__ Wk,
                                                const float* __restrict__ Wv,
                                                ushort_t* __restrict__ Wsw) {
  __shared__ float tile[64][65];
  const float* W = (blockIdx.y == 0) ? Wq : (blockIdx.y == 1 ? Wk : Wv);
  int kt = blockIdx.x, t = threadIdx.x;
  int r = t >> 2, cq = t & 3;
  const float* src = W + (kt * 64 + r) * Hh + cq * 16;
#pragma unroll
  for (int j = 0; j < 16; j += 4) {
    float4 v = *reinterpret_cast<const float4*>(src + j);
    tile[r][cq * 16 + j + 0] = v.x;
    tile[r][cq * 16 + j + 1] = v.y;
    tile[r][cq * 16 + j + 2] = v.z;
    tile[r][cq * 16 + j + 3] = v.w;
  }
  __syncthreads();
  int n = t >> 2, kq = t & 3;
  int rr = blockIdx.y * 64 + n;  // W row 0..191
  ushort_t ob[16];
#pragma unroll
  for (int j = 0; j < 16; ++j) ob[j] = f2bfu(tile[kq * 16 + j][n]);
#pragma unroll
  for (int j = 0; j < 2; ++j) {
    int c16 = 2 * kq + j;
    size_t off = ((size_t)(kt * 192 + rr)) * 64 + (size_t)(((c16 ^ (rr & 7))) * 8);
    *reinterpret_cast<uint4*>(Wsw + off) = reinterpret_cast<uint4*>(ob)[j];
  }
}

// ---------------- fused QKV projection v5: R15 pipeline + (512,2) ----------------
// 256 blocks x 512 thr (8 waves). Tile 64 rows x 192 cols, 16 K-steps of 64.
// W staged async via global_load_lds from pre-swizzled Wsw; A reg-staged,
// issued 2 steps early, pinned by sched_barrier(0). Single barrier per step:
//   { bar; WRITEA(next); GLW(next); LOADA(next+2); COMPUTE(cur) }.
// (512,2): VGPR cap 256 -> natural ~90-110, NO spill (R16's (512,4) squeezed to
// 64 and spilled 60MB); LDS 66KB -> 2 blocks/CU -> 16 waves/CU (2x R17's TLP).
__global__ __launch_bounds__(512, 2) void k_proj(const float* __restrict__ hs,
                                                 const float* __restrict__ bq,
                                                 const float* __restrict__ bk,
                                                 const float* __restrict__ bv,
                                                 const ushort_t* __restrict__ Wsw,
                                                 const int* __restrict__ am,
                                                 ushort_t* __restrict__ qf_,
                                                 ushort_t* __restrict__ kf_,
                                                 ushort_t* __restrict__ vf_,
                                                 float* __restrict__ pen) {
  __shared__ __align__(16) ushort_t bufA[2][64][72];      // 18 KB
  __shared__ __align__(16) ushort_t bufW[2][192 * 64];    // 48 KB

  int t = threadIdx.x, w = t >> 6, l = t & 63, g = l >> 4, c = l & 15;
  int wm = w >> 1, wn = w & 1;
  int row0 = blockIdx.x * 64;

  int ar = t >> 3, ach = t & 7;
  const float* agp = hs + (size_t)(row0 + ar) * Ee + ach * 8;

  f32x4 acc[6];
#pragma unroll
  for (int nt = 0; nt < 6; ++nt) acc[nt] = f32x4{0.f, 0.f, 0.f, 0.f};
  float4 aR0, aR1;

  auto LOADA = [&](int kk) {
    aR0 = *reinterpret_cast<const float4*>(agp + kk);
    aR1 = *reinterpret_cast<const float4*>(agp + kk + 4);
  };
  auto WRITEA = [&](int buf) {
    bf16x8 av;
    av[0] = (__bf16)aR0.x; av[1] = (__bf16)aR0.y; av[2] = (__bf16)aR0.z; av[3] = (__bf16)aR0.w;
    av[4] = (__bf16)aR1.x; av[5] = (__bf16)aR1.y; av[6] = (__bf16)aR1.z; av[7] = (__bf16)aR1.w;
    *reinterpret_cast<bf16x8*>(&bufA[buf][ar][ach * 8]) = av;
  };
  auto GLW = [&](int buf, int s) {
    const ushort_t* base = Wsw + (size_t)s * 12288;
#pragma unroll
    for (int j = 0; j < 3; ++j) {
      int seg = j * 8 + w;                            // 0..23, wave-uniform
      const ushort_t* gp = base + seg * 512 + l * 8;  // per-lane 16B
      gload_lds16(gp, &bufW[buf][seg * 512]);
    }
  };
  auto COMPUTE = [&](int buf) {
    const ushort_t* Ab = &bufA[buf][wm * 16 + c][0];
    bf16x8 af0 = *reinterpret_cast<const bf16x8*>(Ab + g * 8);
    bf16x8 af1 = *reinterpret_cast<const bf16x8*>(Ab + 32 + g * 8);
#pragma unroll
    for (int nt = 0; nt < 6; ++nt) {
      int r = wn * 96 + nt * 16 + c;
      int slot = g ^ (r & 7);
      const ushort_t* Wb = &bufW[buf][r * 64];
      bf16x8 b0 = *reinterpret_cast<const bf16x8*>(Wb + slot * 8);
      bf16x8 b1 = *reinterpret_cast<const bf16x8*>(Wb + (slot ^ 4) * 8);
      acc[nt] = mfma16(af0, b0, acc[nt]);
      acc[nt] = mfma16(af1, b1, acc[nt]);
    }
  };

  // prologue
  LOADA(0);
  WRITEA(0);
  GLW(0, 0);
  LOADA(64);
  __builtin_amdgcn_sched_barrier(0);

  int cur = 0;
  for (int s = 0; s < 16; ++s) {
    __syncthreads();
    if (s < 15) {
      WRITEA(cur ^ 1);
      GLW(cur ^ 1, s + 1);
    }
    if (s < 14) {
      LOADA((s + 2) * 64);
      __builtin_amdgcn_sched_barrier(0);
    }
    COMPUTE(cur);
    cur ^= 1;
  }

  // epilogue: scatter into fragment-major layouts
#pragma unroll
  for (int nt = 0; nt < 6; ++nt) {
    int T = wn * 6 + nt;
    int m = T >> 2;
    int h = (T & 3) * 16 + c;
    const float* bias = (m == 0) ? bq : ((m == 1) ? bk : bv);
    float bb = bias[h];
    int cc = h >> 4, hh = (h >> 3) & 1, jj = h & 7;
    int dt = h >> 5, dl = h & 31;
#pragma unroll
    for (int i = 0; i < 4; ++i) {
      int row = row0 + wm * 16 + g * 4 + i;
      float val = acc[nt][i] + bb;
      int bi = row >> 11, rl = row & 2047;
      if (m == 0) {
        size_t a = ((((size_t)(bi * 64 + (rl >> 5)) * 4 + cc) * 2 + hh) * 32 + (rl & 31)) * 8 + jj;
        qf_[a] = f2bfu(val * SCLQ);
      } else if (m == 1) {
        size_t a = ((((size_t)(bi * 64 + (rl >> 5)) * 4 + cc) * 2 + hh) * 32 + (rl & 31)) * 8 + jj;
        kf_[a] = f2bfu(val);
      } else {
        int s16 = rl >> 4, vh = (rl >> 3) & 1, vj = rl & 7;
        size_t a = ((((size_t)(bi * 128 + s16) * 2 + dt) * 2 + vh) * 32 + dl) * 8 + vj;
        vf_[a] = f2bfu(val);
      }
    }
  }

  if (t < 64) {
    int grow = row0 + t;
    int bi = grow >> 11, s2 = grow & 2047;
    int mv = am[grow];
    pen[((size_t)bi * 2 + 0) * Ss + s2] = mv ? 0.f : NEG2;
    pen[((size_t)bi * 2 + 1) * Ss + s2] = mv ? NEG2 : 0.f;
  }
}

// ---------------- fused masked flash attention (R13, measured ~21.6us) ----
// grid 1024: b = bid&7 (batch-per-XCD), qt = (bid>>3)&63, kh = bid>>9 (k-split).
// 256 thr / 4 waves; wave w owns keys [kh*1024 + w*256, +256). Every K/V/Q
// fragment load is ONE coalesced b128 (L2-resident); no LDS staging, no loop
// barriers; launch_bounds(256,3) (cap ~170; (256,4) spills — R12).
// Fixed m=0 softmax -> k-split partials are plain sums; k_fin combines.
__global__ __launch_bounds__(256, 3) void k_attn(const ushort_t* __restrict__ qs,
                                                 const ushort_t* __restrict__ km,
                                                 const ushort_t* __restrict__ vm,
                                                 const int* __restrict__ am,
                                                 const float* __restrict__ pen,
                                                 float* __restrict__ opart,
                                                 float* __restrict__ lpart) {
  __shared__ float obuf[4][32][68];
  __shared__ float lls[4][32];

  int t = threadIdx.x, w = t >> 6, l = t & 63, lo = l & 31, hi = l >> 5;
  int bid = blockIdx.x;
  int b = bid & 7, qt = (bid >> 3) & 63, kh = bid >> 9;
  int q0 = qt * 32;

  const size_t laneoff = (size_t)hi * 256 + lo * 8;

  const ushort_t* qbase = qs + (size_t)(b * 64 + qt) * 2048 + laneoff;
  bf16x8 qf[4];
#pragma unroll
  for (int c = 0; c < 4; ++c)
    qf[c] = *reinterpret_cast<const bf16x8*>(qbase + (size_t)c * 512);

  int mq = am[b * Ss + q0 + lo];
  float negq = mq ? NEG2 : 0.f;
  const float* psel = pen + ((size_t)b * 2 + (mq ? 0 : 1)) * Ss;

  float ll = 0.f;
  f32x16 o0 = {0.f, 0.f, 0.f, 0.f, 0.f, 0.f, 0.f, 0.f, 0.f, 0.f, 0.f, 0.f, 0.f, 0.f, 0.f, 0.f};
  f32x16 o1 = o0;
  const f32x16 z16 = o0;

  const int kvbeg = kh * 1024 + w * 256;
  const ushort_t* kb = km + (size_t)b * 131072 + laneoff;
  const ushort_t* vb = vm + (size_t)b * 131072 + laneoff;

  for (int it = 0; it < 8; ++it) {
    const int kv0 = kvbeg + it * 32;
    const int kt32 = kv0 >> 5, s16 = kv0 >> 4;

    const ushort_t* kfp = kb + (size_t)kt32 * 2048;
    bf16x8 kf0 = *reinterpret_cast<const bf16x8*>(kfp);
    bf16x8 kf1 = *reinterpret_cast<const bf16x8*>(kfp + 512);
    bf16x8 kf2 = *reinterpret_cast<const bf16x8*>(kfp + 1024);
    bf16x8 kf3 = *reinterpret_cast<const bf16x8*>(kfp + 1536);
    const ushort_t* vfp = vb + (size_t)s16 * 1024;
    bf16x8 vf00 = *reinterpret_cast<const bf16x8*>(vfp);
    bf16x8 vf01 = *reinterpret_cast<const bf16x8*>(vfp + 512);
    bf16x8 vf10 = *reinterpret_cast<const bf16x8*>(vfp + 1024);
    bf16x8 vf11 = *reinterpret_cast<const bf16x8*>(vfp + 1536);

    f32x4 pv[4];
#pragma unroll
    for (int j = 0; j < 4; ++j)
      pv[j] = *reinterpret_cast<const f32x4*>(psel + kv0 + j * 8 + hi * 4);

    f32x16 sc = mfma32(kf0, qf[0], z16);
    sc = mfma32(kf1, qf[1], sc);
    sc = mfma32(kf2, qf[2], sc);
    sc = mfma32(kf3, qf[3], sc);

    if (kv0 == q0) {
#pragma unroll
      for (int r = 0; r < 16; ++r) {
        int kr = (r & 3) + 8 * (r >> 2) + 4 * hi;
        sc[r] += pv[r >> 2][r & 3] + ((kr > lo) ? negq : 0.f);
      }
    } else {
      float addt = (kv0 > q0) ? negq : 0.f;
#pragma unroll
      for (int r = 0; r < 16; ++r) sc[r] += pv[r >> 2][r & 3] + addt;
    }

    float p[16], ts = 0.f;
#pragma unroll
    for (int r = 0; r < 16; ++r) {
      p[r] = __builtin_amdgcn_exp2f(sc[r]);
      ts += p[r];
    }
    ll += ts;

    unsigned x0 = cvtpk(p[0], p[1]), y0 = cvtpk(p[2], p[3]);
    unsigned z0 = cvtpk(p[4], p[5]), w0 = cvtpk(p[6], p[7]);
    swap32(x0, z0);
    swap32(y0, w0);
    unsigned x1 = cvtpk(p[8], p[9]), y1 = cvtpk(p[10], p[11]);
    unsigned z1 = cvtpk(p[12], p[13]), w1 = cvtpk(p[14], p[15]);
    swap32(x1, z1);
    swap32(y1, w1);
    bf16x8 pa0 = __builtin_bit_cast(bf16x8, u32x4{x0, y0, z0, w0});
    bf16x8 pa1 = __builtin_bit_cast(bf16x8, u32x4{x1, y1, z1, w1});

    o0 = mfma32(pa0, vf00, o0);
    o0 = mfma32(pa1, vf10, o0);
    o1 = mfma32(pa0, vf01, o1);
    o1 = mfma32(pa1, vf11, o1);
  }

  ll += __shfl_xor(ll, 32);

#pragma unroll
  for (int r = 0; r < 16; ++r) {
    int qrow = (r & 3) + 8 * (r >> 2) + 4 * hi;
    obuf[w][qrow][lo] = o0[r];
    obuf[w][qrow][32 + lo] = o1[r];
  }
  if (hi == 0) lls[w][lo] = ll;
  __syncthreads();

  int qr = t >> 3, dg = t & 7;
  float lg = lls[0][qr] + lls[1][qr] + lls[2][qr] + lls[3][qr];
  float a8[8] = {0.f, 0.f, 0.f, 0.f, 0.f, 0.f, 0.f, 0.f};
#pragma unroll
  for (int ww = 0; ww < 4; ++ww) {
    float4 c0 = *reinterpret_cast<const float4*>(&obuf[ww][qr][dg * 8]);
    float4 c1 = *reinterpret_cast<const float4*>(&obuf[ww][qr][dg * 8 + 4]);
    a8[0] += c0.x; a8[1] += c0.y; a8[2] += c0.z; a8[3] += c0.w;
    a8[4] += c1.x; a8[5] += c1.y; a8[6] += c1.z; a8[7] += c1.w;
  }
  float* op = opart + (((size_t)kh * 8 + b) * Ss + q0 + qr) * 64 + dg * 8;
  float4 r0v = {a8[0], a8[1], a8[2], a8[3]};
  float4 r1v = {a8[4], a8[5], a8[6], a8[7]};
  *reinterpret_cast<float4*>(op) = r0v;
  *reinterpret_cast<float4*>(op + 4) = r1v;
  if (dg == 0) lpart[((size_t)kh * 8 + b) * Ss + q0 + qr] = lg;
}

// ---------------- finalize: out = (opart0 + opart1) / (l0 + l1) ----------------
__global__ __launch_bounds__(256) void k_fin(const float* __restrict__ op,
                                             const float* __restrict__ lp,
                                             float* __restrict__ out) {
  int gi = blockIdx.x * 256 + threadIdx.x;
  int row = gi >> 4;
  float lsum = lp[row] + lp[row + 16384];
  f32x4 a = reinterpret_cast<const f32x4*>(op)[gi];
  f32x4 b = reinterpret_cast<const f32x4*>(op)[gi + 262144];
  float inv = 1.f / lsum;
  f32x4 r = (a + b) * inv;
  reinterpret_cast<f32x4*>(out)[gi] = r;
}

extern "C" void kernel_launch(void* const* d_in, const int* in_sizes, int n_in,
                              void* d_out, int out_size, void* d_ws, size_t ws_size,
                              hipStream_t stream) {
  const float* hs = (const float*)d_in[0];
  const int* am = (const int*)d_in[1];
  const float* Wq = (const float*)d_in[2];
  const float* bq = (const float*)d_in[3];
  const float* Wk = (const float*)d_in[4];
  const float* bk = (const float*)d_in[5];
  const float* Wv = (const float*)d_in[6];
  const float* bv = (const float*)d_in[7];
  float* out = (float*)d_out;

  char* ws = (char*)d_ws;
  ushort_t* qsp = (ushort_t*)(ws + 0);                  // 2 MB: Q fragment-major, scaled
  ushort_t* kp = (ushort_t*)(ws + (2u << 20));          // 2 MB: K fragment-major
  ushort_t* vtp = (ushort_t*)(ws + (4u << 20));         // 2 MB: V fragment-major
  ushort_t* wtp = (ushort_t*)(ws + (6u << 20));         // 384 KB: Wsw pre-swizzled
  float* penp = (float*)(ws + (6u << 20) + (512u << 10));  // 128 KB: [B][2][S] f32
  float* opart = (float*)(ws + (8u << 20));             // 8 MB: [2][B][S][64] f32
  float* lpart = (float*)(ws + (16u << 20));            // 128 KB: [2][B][S] f32

  k_wtrans<<<dim3(16, 3), 256, 0, stream>>>(Wq, Wk, Wv, wtp);
  k_proj<<<dim3(256), 512, 0, stream>>>(hs, bq, bk, bv, wtp, am, qsp, kp, vtp, penp);
  k_attn<<<dim3(1024), 256, 0, stream>>>(qsp, kp, vtp, am, penp, opart, lpart);
  k_fin<<<dim3(1024), 256, 0, stream>>>(opart, lpart, out);
}

// Round 20
// 47.362 us; speedup vs baseline: 1.5541x; 1.1484x over previous
//
#include <hip/hip_runtime.h>

typedef float f32x4 __attribute__((ext_vector_type(4)));
typedef float f32x16 __attribute__((ext_vector_type(16)));
typedef unsigned int u32x4 __attribute__((ext_vector_type(4)));
typedef __bf16 bf16x8 __attribute__((ext_vector_type(8)));
typedef unsigned short ushort_t;

#define NEG2 (-144269.5f)   /* -1e5 * log2(e) */
#define SCLQ (0.18033688f)  /* 0.125 * log2(e) */

constexpr int Ss = 2048, Ee = 1024, Hh = 64;

static __device__ __forceinline__ ushort_t f2bfu(float f) {
  return __builtin_bit_cast(ushort_t, (__bf16)f);
}
static __device__ __forceinline__ f32x4 mfma16(bf16x8 a, bf16x8 b, f32x4 c) {
  return __builtin_amdgcn_mfma_f32_16x16x32_bf16(a, b, c, 0, 0, 0);
}
static __device__ __forceinline__ f32x16 mfma32(bf16x8 a, bf16x8 b, f32x16 c) {
  return __builtin_amdgcn_mfma_f32_32x32x16_bf16(a, b, c, 0, 0, 0);
}
static __device__ __forceinline__ unsigned cvtpk(float a, float b) {
  unsigned r;
  asm("v_cvt_pk_bf16_f32 %0, %1, %2" : "=v"(r) : "v"(a), "v"(b));
  return r;
}
// NOTE: only call with a,b holding DIFFERENT values (R3 bug).
static __device__ __forceinline__ void swap32(unsigned& a, unsigned& b) {
  asm("v_permlane32_swap_b32 %0, %1" : "+v"(a), "+v"(b));
}
// async global->LDS, 16B per lane; LDS dest = uniform base + lane*16 (m104)
static __device__ __forceinline__ void gload_lds16(const void* g, void* l) {
  __builtin_amdgcn_global_load_lds(
      (const __attribute__((address_space(1))) unsigned int*)g,
      (__attribute__((address_space(3))) unsigned int*)l, 16, 0, 0);
}

// ============ Fragment-major layouts (ushort element offsets) ============
// Q/K: F(b,t32,c,hi,lo,j) = ((((b*64+t32)*4+c)*2+hi)*32+lo)*8+j
// V:   G(b,s16,dt,hi,lo,j) = ((((b*128+s16)*2+dt)*2+hi)*32+lo)*8+j
// Wsw: off = (s*192 + r)*64 + ((c16 ^ (r&7)) * 8)
// HISTORY: proj: R16 spill diag 34us -> R17 (512blk x 256thr,(256,2)) ~22us
// [best total 52.6]; R18 W-direct-L2 regressed; R19 TLP-doubling neutral.
// attn: R16-measured ~21.6us; theory now = per-XCD L2 BW x re-read factor
// (290KB/block x 128 blocks/XCD / 4.3TB/s ~ 8.6us floor). R20: 2 q-tiles per
// wave share K/V regs -> L2 traffic halves + 2x ILP between loads.

// ---------------- weight transpose + bf16 convert -> Wsw ----------------
__global__ __launch_bounds__(256) void k_wtrans(const float* __restrict__ Wq,
                                                const float* __restrict__ Wk,
                                                const float* __restrict__ Wv,
                                                ushort_t* __restrict__ Wsw) {
  __shared__ float tile[64][65];
  const float* W = (blockIdx.y == 0) ? Wq : (blockIdx.y == 1 ? Wk : Wv);
  int kt = blockIdx.x, t = threadIdx.x;
  int r = t >> 2, cq = t & 3;
  const float* src = W + (kt * 64 + r) * Hh + cq * 16;
#pragma unroll
  for (int j = 0; j < 16; j += 4) {
    float4 v = *reinterpret_cast<const float4*>(src + j);
    tile[r][cq * 16 + j + 0] = v.x;
    tile[r][cq * 16 + j + 1] = v.y;
    tile[r][cq * 16 + j + 2] = v.z;
    tile[r][cq * 16 + j + 3] = v.w;
  }
  __syncthreads();
  int n = t >> 2, kq = t & 3;
  int rr = blockIdx.y * 64 + n;  // W row 0..191
  ushort_t ob[16];
#pragma unroll
  for (int j = 0; j < 16; ++j) ob[j] = f2bfu(tile[kq * 16 + j][n]);
#pragma unroll
  for (int j = 0; j < 2; ++j) {
    int c16 = 2 * kq + j;
    size_t off = ((size_t)(kt * 192 + rr)) * 64 + (size_t)(((c16 ^ (rr & 7))) * 8);
    *reinterpret_cast<uint4*>(Wsw + off) = reinterpret_cast<uint4*>(ob)[j];
  }
}

// ---------------- fused QKV projection (R17 config — best total) ----------------
// 512 blocks x 256 thr, (256,2): VGPR cap 256 (no spill), 57KB LDS -> 2
// blocks/CU, 8 waves/CU. W staged async via global_load_lds from pre-swizzled
// Wsw; A reg-staged, issued 2 steps early, pinned by sched_barrier(0).
// Single barrier per step: { bar; WRITEA(next); GLW(next); LOADA(next+2); COMPUTE }.
__global__ __launch_bounds__(256, 2) void k_proj(const float* __restrict__ hs,
                                                 const float* __restrict__ bq,
                                                 const float* __restrict__ bk,
                                                 const float* __restrict__ bv,
                                                 const ushort_t* __restrict__ Wsw,
                                                 const int* __restrict__ am,
                                                 ushort_t* __restrict__ qf_,
                                                 ushort_t* __restrict__ kf_,
                                                 ushort_t* __restrict__ vf_,
                                                 float* __restrict__ pen) {
  __shared__ __align__(16) ushort_t bufA[2][32][72];      // 9 KB
  __shared__ __align__(16) ushort_t bufW[2][192 * 64];    // 48 KB

  int t = threadIdx.x, w = t >> 6, l = t & 63, g = l >> 4, c = l & 15;
  int wm = w >> 1, wn = w & 1;
  int row0 = blockIdx.x * 32;

  int ar = t >> 3, ach = t & 7;  // 32 rows x 8 16B-chunks
  const float* agp = hs + (size_t)(row0 + ar) * Ee + ach * 8;

  f32x4 acc[6];
#pragma unroll
  for (int nt = 0; nt < 6; ++nt) acc[nt] = f32x4{0.f, 0.f, 0.f, 0.f};
  float4 aR0, aR1;

  auto LOADA = [&](int kk) {
    aR0 = *reinterpret_cast<const float4*>(agp + kk);
    aR1 = *reinterpret_cast<const float4*>(agp + kk + 4);
  };
  auto WRITEA = [&](int buf) {
    bf16x8 av;
    av[0] = (__bf16)aR0.x; av[1] = (__bf16)aR0.y; av[2] = (__bf16)aR0.z; av[3] = (__bf16)aR0.w;
    av[4] = (__bf16)aR1.x; av[5] = (__bf16)aR1.y; av[6] = (__bf16)aR1.z; av[7] = (__bf16)aR1.w;
    *reinterpret_cast<bf16x8*>(&bufA[buf][ar][ach * 8]) = av;
  };
  auto GLW = [&](int buf, int s) {
    const ushort_t* base = Wsw + (size_t)s * 12288;
#pragma unroll
    for (int j = 0; j < 6; ++j) {
      int seg = j * 4 + w;                            // 0..23, wave-uniform
      const ushort_t* gp = base + seg * 512 + l * 8;  // per-lane 16B
      gload_lds16(gp, &bufW[buf][seg * 512]);
    }
  };
  auto COMPUTE = [&](int buf) {
    const ushort_t* Ab = &bufA[buf][wm * 16 + c][0];
    bf16x8 af0 = *reinterpret_cast<const bf16x8*>(Ab + g * 8);
    bf16x8 af1 = *reinterpret_cast<const bf16x8*>(Ab + 32 + g * 8);
#pragma unroll
    for (int nt = 0; nt < 6; ++nt) {
      int r = wn * 96 + nt * 16 + c;
      int slot = g ^ (r & 7);
      const ushort_t* Wb = &bufW[buf][r * 64];
      bf16x8 b0 = *reinterpret_cast<const bf16x8*>(Wb + slot * 8);
      bf16x8 b1 = *reinterpret_cast<const bf16x8*>(Wb + (slot ^ 4) * 8);
      acc[nt] = mfma16(af0, b0, acc[nt]);
      acc[nt] = mfma16(af1, b1, acc[nt]);
    }
  };

  // prologue
  LOADA(0);
  WRITEA(0);
  GLW(0, 0);
  LOADA(64);
  __builtin_amdgcn_sched_barrier(0);

  int cur = 0;
  for (int s = 0; s < 16; ++s) {
    __syncthreads();
    if (s < 15) {
      WRITEA(cur ^ 1);
      GLW(cur ^ 1, s + 1);
    }
    if (s < 14) {
      LOADA((s + 2) * 64);
      __builtin_amdgcn_sched_barrier(0);
    }
    COMPUTE(cur);
    cur ^= 1;
  }

  // epilogue: scatter into fragment-major layouts
#pragma unroll
  for (int nt = 0; nt < 6; ++nt) {
    int T = wn * 6 + nt;
    int m = T >> 2;
    int h = (T & 3) * 16 + c;
    const float* bias = (m == 0) ? bq : ((m == 1) ? bk : bv);
    float bb = bias[h];
    int cc = h >> 4, hh = (h >> 3) & 1, jj = h & 7;
    int dt = h >> 5, dl = h & 31;
#pragma unroll
    for (int i = 0; i < 4; ++i) {
      int row = row0 + wm * 16 + g * 4 + i;
      float val = acc[nt][i] + bb;
      int bi = row >> 11, rl = row & 2047;
      if (m == 0) {
        size_t a = ((((size_t)(bi * 64 + (rl >> 5)) * 4 + cc) * 2 + hh) * 32 + (rl & 31)) * 8 + jj;
        qf_[a] = f2bfu(val * SCLQ);
      } else if (m == 1) {
        size_t a = ((((size_t)(bi * 64 + (rl >> 5)) * 4 + cc) * 2 + hh) * 32 + (rl & 31)) * 8 + jj;
        kf_[a] = f2bfu(val);
      } else {
        int s16 = rl >> 4, vh = (rl >> 3) & 1, vj = rl & 7;
        size_t a = ((((size_t)(bi * 128 + s16) * 2 + dt) * 2 + vh) * 32 + dl) * 8 + vj;
        vf_[a] = f2bfu(val);
      }
    }
  }

  if (t < 32) {
    int grow = row0 + t;
    int bi = grow >> 11, s2 = grow & 2047;
    int mv = am[grow];
    pen[((size_t)bi * 2 + 0) * Ss + s2] = mv ? 0.f : NEG2;
    pen[((size_t)bi * 2 + 1) * Ss + s2] = mv ? NEG2 : 0.f;
  }
}

// ---------------- fused masked flash attention v5: 2 q-tiles per wave ----------------
// grid 512: b = bid&7 (batch-per-XCD), qt2 = (bid>>3)&31 (64-q double-tile),
// kh = bid>>8 (k-split half). 256 thr / 4 waves; wave w owns keys
// [kh*1024 + w*256, +256) = 8 tiles of 32. Each wave processes q-tiles
// A = qt2*2, B = qt2*2+1 SHARING one set of K/V fragment registers: per-XCD L2
// K/V traffic halves (the R20 theory) and QK_B/PV_A overlap softmax_A/B (2x
// ILP). Sequential softmax keeps liveness ~210-230 VGPR under the (256,2)
// cap of 256. Fixed m=0 softmax -> k-split partials are plain sums; k_fin.
__global__ __launch_bounds__(256, 2) void k_attn(const ushort_t* __restrict__ qs,
                                                 const ushort_t* __restrict__ km,
                                                 const ushort_t* __restrict__ vm,
                                                 const int* __restrict__ am,
                                                 const float* __restrict__ pen,
                                                 float* __restrict__ opart,
                                                 float* __restrict__ lpart) {
  __shared__ float obuf[4][64][68];   // 69.6 KB
  __shared__ float lls[4][64];

  int t = threadIdx.x, w = t >> 6, l = t & 63, lo = l & 31, hi = l >> 5;
  int bid = blockIdx.x;
  int b = bid & 7, qt2 = (bid >> 3) & 31, kh = bid >> 8;
  int q0A = qt2 * 64, q0B = q0A + 32;

  const size_t laneoff = (size_t)hi * 256 + lo * 8;

  // Q B-frags for both tiles
  const ushort_t* qbaseA = qs + (size_t)(b * 64 + qt2 * 2) * 2048 + laneoff;
  const ushort_t* qbaseB = qbaseA + 2048;
  bf16x8 qfA[4], qfB[4];
#pragma unroll
  for (int c = 0; c < 4; ++c) {
    qfA[c] = *reinterpret_cast<const bf16x8*>(qbaseA + (size_t)c * 512);
    qfB[c] = *reinterpret_cast<const bf16x8*>(qbaseB + (size_t)c * 512);
  }

  int mqA = am[b * Ss + q0A + lo], mqB = am[b * Ss + q0B + lo];
  float negqA = mqA ? NEG2 : 0.f, negqB = mqB ? NEG2 : 0.f;
  const float* pselA = pen + ((size_t)b * 2 + (mqA ? 0 : 1)) * Ss;
  const float* pselB = pen + ((size_t)b * 2 + (mqB ? 0 : 1)) * Ss;

  float llA = 0.f, llB = 0.f;
  f32x16 o0A = {0.f, 0.f, 0.f, 0.f, 0.f, 0.f, 0.f, 0.f, 0.f, 0.f, 0.f, 0.f, 0.f, 0.f, 0.f, 0.f};
  f32x16 o1A = o0A, o0B = o0A, o1B = o0A;
  const f32x16 z16 = o0A;

  const int kvbeg = kh * 1024 + w * 256;
  const ushort_t* kb = km + (size_t)b * 131072 + laneoff;
  const ushort_t* vb = vm + (size_t)b * 131072 + laneoff;

  for (int it = 0; it < 8; ++it) {
    const int kv0 = kvbeg + it * 32;
    const int kt32 = kv0 >> 5, s16 = kv0 >> 4;

    // shared K/V fragment loads (serve BOTH q-tiles)
    const ushort_t* kfp = kb + (size_t)kt32 * 2048;
    bf16x8 kf0 = *reinterpret_cast<const bf16x8*>(kfp);
    bf16x8 kf1 = *reinterpret_cast<const bf16x8*>(kfp + 512);
    bf16x8 kf2 = *reinterpret_cast<const bf16x8*>(kfp + 1024);
    bf16x8 kf3 = *reinterpret_cast<const bf16x8*>(kfp + 1536);
    const ushort_t* vfp = vb + (size_t)s16 * 1024;
    bf16x8 vf00 = *reinterpret_cast<const bf16x8*>(vfp);
    bf16x8 vf01 = *reinterpret_cast<const bf16x8*>(vfp + 512);
    bf16x8 vf10 = *reinterpret_cast<const bf16x8*>(vfp + 1024);
    bf16x8 vf11 = *reinterpret_cast<const bf16x8*>(vfp + 1536);

    f32x4 pvA[4];
#pragma unroll
    for (int j = 0; j < 4; ++j)
      pvA[j] = *reinterpret_cast<const f32x4*>(pselA + kv0 + j * 8 + hi * 4);

    // ---- QK for both tiles (independent chains feed the MFMA pipe) ----
    f32x16 scA = mfma32(kf0, qfA[0], z16);
    scA = mfma32(kf1, qfA[1], scA);
    scA = mfma32(kf2, qfA[2], scA);
    scA = mfma32(kf3, qfA[3], scA);
    f32x16 scB = mfma32(kf0, qfB[0], z16);
    scB = mfma32(kf1, qfB[1], scB);
    scB = mfma32(kf2, qfB[2], scB);
    scB = mfma32(kf3, qfB[3], scB);

    // ---- tile A: mask + softmax + PV ----
    if (kv0 == q0A) {
#pragma unroll
      for (int r = 0; r < 16; ++r) {
        int kr = (r & 3) + 8 * (r >> 2) + 4 * hi;
        scA[r] += pvA[r >> 2][r & 3] + ((kr > lo) ? negqA : 0.f);
      }
    } else {
      float addt = (kv0 > q0A) ? negqA : 0.f;
#pragma unroll
      for (int r = 0; r < 16; ++r) scA[r] += pvA[r >> 2][r & 3] + addt;
    }
    float pA[16], tsA = 0.f;
#pragma unroll
    for (int r = 0; r < 16; ++r) {
      pA[r] = __builtin_amdgcn_exp2f(scA[r]);
      tsA += pA[r];
    }
    llA += tsA;
    unsigned xa0 = cvtpk(pA[0], pA[1]), ya0 = cvtpk(pA[2], pA[3]);
    unsigned za0 = cvtpk(pA[4], pA[5]), wa0 = cvtpk(pA[6], pA[7]);
    swap32(xa0, za0);
    swap32(ya0, wa0);
    unsigned xa1 = cvtpk(pA[8], pA[9]), ya1 = cvtpk(pA[10], pA[11]);
    unsigned za1 = cvtpk(pA[12], pA[13]), wa1 = cvtpk(pA[14], pA[15]);
    swap32(xa1, za1);
    swap32(ya1, wa1);
    bf16x8 paA0 = __builtin_bit_cast(bf16x8, u32x4{xa0, ya0, za0, wa0});
    bf16x8 paA1 = __builtin_bit_cast(bf16x8, u32x4{xa1, ya1, za1, wa1});
    o0A = mfma32(paA0, vf00, o0A);
    o0A = mfma32(paA1, vf10, o0A);
    o1A = mfma32(paA0, vf01, o1A);
    o1A = mfma32(paA1, vf11, o1A);

    // pvB loaded late (use is ~100cyc away) to shave peak register liveness
    f32x4 pvB[4];
#pragma unroll
    for (int j = 0; j < 4; ++j)
      pvB[j] = *reinterpret_cast<const f32x4*>(pselB + kv0 + j * 8 + hi * 4);

    // ---- tile B: mask + softmax + PV (overlaps PV_A on MFMA pipe) ----
    if (kv0 == q0B) {
#pragma unroll
      for (int r = 0; r < 16; ++r) {
        int kr = (r & 3) + 8 * (r >> 2) + 4 * hi;
        scB[r] += pvB[r >> 2][r & 3] + ((kr > lo) ? negqB : 0.f);
      }
    } else {
      float addt = (kv0 > q0B) ? negqB : 0.f;
#pragma unroll
      for (int r = 0; r < 16; ++r) scB[r] += pvB[r >> 2][r & 3] + addt;
    }
    float pB[16], tsB = 0.f;
#pragma unroll
    for (int r = 0; r < 16; ++r) {
      pB[r] = __builtin_amdgcn_exp2f(scB[r]);
      tsB += pB[r];
    }
    llB += tsB;
    unsigned xb0 = cvtpk(pB[0], pB[1]), yb0 = cvtpk(pB[2], pB[3]);
    unsigned zb0 = cvtpk(pB[4], pB[5]), wb0 = cvtpk(pB[6], pB[7]);
    swap32(xb0, zb0);
    swap32(yb0, wb0);
    unsigned xb1 = cvtpk(pB[8], pB[9]), yb1 = cvtpk(pB[10], pB[11]);
    unsigned zb1 = cvtpk(pB[12], pB[13]), wb1 = cvtpk(pB[14], pB[15]);
    swap32(xb1, zb1);
    swap32(yb1, wb1);
    bf16x8 paB0 = __builtin_bit_cast(bf16x8, u32x4{xb0, yb0, zb0, wb0});
    bf16x8 paB1 = __builtin_bit_cast(bf16x8, u32x4{xb1, yb1, zb1, wb1});
    o0B = mfma32(paB0, vf00, o0B);
    o0B = mfma32(paB1, vf10, o0B);
    o1B = mfma32(paB0, vf01, o1B);
    o1B = mfma32(paB1, vf11, o1B);
  }

  llA += __shfl_xor(llA, 32);
  llB += __shfl_xor(llB, 32);

  // ---- stash both tiles' partials ----
#pragma unroll
  for (int r = 0; r < 16; ++r) {
    int qrow = (r & 3) + 8 * (r >> 2) + 4 * hi;
    obuf[w][qrow][lo] = o0A[r];
    obuf[w][qrow][32 + lo] = o1A[r];
    obuf[w][32 + qrow][lo] = o0B[r];
    obuf[w][32 + qrow][32 + lo] = o1B[r];
  }
  if (hi == 0) {
    lls[w][lo] = llA;
    lls[w][32 + lo] = llB;
  }
  __syncthreads();

  // ---- combine 4 waves' partials, 2 passes over 64 rows ----
  int qr = t >> 3, dg = t & 7;
#pragma unroll
  for (int pass = 0; pass < 2; ++pass) {
    int row = pass * 32 + qr;
    float lg = lls[0][row] + lls[1][row] + lls[2][row] + lls[3][row];
    float a8[8] = {0.f, 0.f, 0.f, 0.f, 0.f, 0.f, 0.f, 0.f};
#pragma unroll
    for (int ww = 0; ww < 4; ++ww) {
      float4 c0 = *reinterpret_cast<const float4*>(&obuf[ww][row][dg * 8]);
      float4 c1 = *reinterpret_cast<const float4*>(&obuf[ww][row][dg * 8 + 4]);
      a8[0] += c0.x; a8[1] += c0.y; a8[2] += c0.z; a8[3] += c0.w;
      a8[4] += c1.x; a8[5] += c1.y; a8[6] += c1.z; a8[7] += c1.w;
    }
    float* op = opart + (((size_t)kh * 8 + b) * Ss + q0A + row) * 64 + dg * 8;
    float4 r0v = {a8[0], a8[1], a8[2], a8[3]};
    float4 r1v = {a8[4], a8[5], a8[6], a8[7]};
    *reinterpret_cast<float4*>(op) = r0v;
    *reinterpret_cast<float4*>(op + 4) = r1v;
    if (dg == 0) lpart[((size_t)kh * 8 + b) * Ss + q0A + row] = lg;
  }
}

// ---------------- finalize: out = (opart0 + opart1) / (l0 + l1) ----------------
__global__ __launch_bounds__(256) void k_fin(const float* __restrict__ op,
                                             const float* __restrict__ lp,
                                             float* __restrict__ out) {
  int gi = blockIdx.x * 256 + threadIdx.x;
  int row = gi >> 4;
  float lsum = lp[row] + lp[row + 16384];
  f32x4 a = reinterpret_cast<const f32x4*>(op)[gi];
  f32x4 b = reinterpret_cast<const f32x4*>(op)[gi + 262144];
  float inv = 1.f / lsum;
  f32x4 r = (a + b) * inv;
  reinterpret_cast<f32x4*>(out)[gi] = r;
}

extern "C" void kernel_launch(void* const* d_in, const int* in_sizes, int n_in,
                              void* d_out, int out_size, void* d_ws, size_t ws_size,
                              hipStream_t stream) {
  const float* hs = (const float*)d_in[0];
  const int* am = (const int*)d_in[1];
  const float* Wq = (const float*)d_in[2];
  const float* bq = (const float*)d_in[3];
  const float* Wk = (const float*)d_in[4];
  const float* bk = (const float*)d_in[5];
  const float* Wv = (const float*)d_in[6];
  const float* bv = (const float*)d_in[7];
  float* out = (float*)d_out;

  char* ws = (char*)d_ws;
  ushort_t* qsp = (ushort_t*)(ws + 0);                  // 2 MB: Q fragment-major, scaled
  ushort_t* kp = (ushort_t*)(ws + (2u << 20));          // 2 MB: K fragment-major
  ushort_t* vtp = (ushort_t*)(ws + (4u << 20));         // 2 MB: V fragment-major
  ushort_t* wtp = (ushort_t*)(ws + (6u << 20));         // 384 KB: Wsw pre-swizzled
  float* penp = (float*)(ws + (6u << 20) + (512u << 10));  // 128 KB: [B][2][S] f32
  float* opart = (float*)(ws + (8u << 20));             // 8 MB: [2][B][S][64] f32
  float* lpart = (float*)(ws + (16u << 20));            // 128 KB: [2][B][S] f32

  k_wtrans<<<dim3(16, 3), 256, 0, stream>>>(Wq, Wk, Wv, wtp);
  k_proj<<<dim3(512), 256, 0, stream>>>(hs, bq, bk, bv, wtp, am, qsp, kp, vtp, penp);
  k_attn<<<dim3(512), 256, 0, stream>>>(qsp, kp, vtp, am, penp, opart, lpart);
  k_fin<<<dim3(1024), 256, 0, stream>>>(opart, lpart, out);
}

// Round 21
// 44.685 us; speedup vs baseline: 1.6472x; 1.0599x over previous
//
#include <hip/hip_runtime.h>

typedef float f32x4 __attribute__((ext_vector_type(4)));
typedef float f32x16 __attribute__((ext_vector_type(16)));
typedef unsigned int u32x4 __attribute__((ext_vector_type(4)));
typedef __bf16 bf16x8 __attribute__((ext_vector_type(8)));
typedef unsigned short ushort_t;

#define NEG2 (-144269.5f)   /* -1e5 * log2(e) */
#define SCLQ (0.18033688f)  /* 0.125 * log2(e) */

constexpr int Ss = 2048, Ee = 1024, Hh = 64;

static __device__ __forceinline__ ushort_t f2bfu(float f) {
  return __builtin_bit_cast(ushort_t, (__bf16)f);
}
static __device__ __forceinline__ f32x4 mfma16(bf16x8 a, bf16x8 b, f32x4 c) {
  return __builtin_amdgcn_mfma_f32_16x16x32_bf16(a, b, c, 0, 0, 0);
}
static __device__ __forceinline__ f32x16 mfma32(bf16x8 a, bf16x8 b, f32x16 c) {
  return __builtin_amdgcn_mfma_f32_32x32x16_bf16(a, b, c, 0, 0, 0);
}
static __device__ __forceinline__ unsigned cvtpk(float a, float b) {
  unsigned r;
  asm("v_cvt_pk_bf16_f32 %0, %1, %2" : "=v"(r) : "v"(a), "v"(b));
  return r;
}
// NOTE: only call with a,b holding DIFFERENT values (R3 bug).
static __device__ __forceinline__ void swap32(unsigned& a, unsigned& b) {
  asm("v_permlane32_swap_b32 %0, %1" : "+v"(a), "+v"(b));
}
// async global->LDS, 16B per lane; LDS dest = uniform base + lane*16 (m104)
static __device__ __forceinline__ void gload_lds16(const void* g, void* l) {
  __builtin_amdgcn_global_load_lds(
      (const __attribute__((address_space(1))) unsigned int*)g,
      (__attribute__((address_space(3))) unsigned int*)l, 16, 0, 0);
}

// ============ Fragment-major layouts (ushort element offsets) ============
// Q/K: F(b,t32,c,hi,lo,j) = ((((b*64+t32)*4+c)*2+hi)*32+lo)*8+j
// V:   G(b,s16,dt,hi,lo,j) = ((((b*128+s16)*2+dt)*2+hi)*32+lo)*8+j
// Wsw: off = (s*192 + r)*64 + ((c16 ^ (r&7)) * 8)
// HISTORY: proj: R16 spill diag 34us -> R17 (512blk x 256thr,(256,2)) ~22us;
// R18 W-direct-L2 regressed; R19 TLP-doubling neutral. attn: R20 2-q-tiles/wave
// sharing K/V regs (L2 traffic halved) 21.6 -> ~16us [total 47.4].
// R21: drop k-split; in-kernel 2-stage LDS combine; k_fin + opart round-trip gone.

// ---------------- weight transpose + bf16 convert -> Wsw ----------------
__global__ __launch_bounds__(256) void k_wtrans(const float* __restrict__ Wq,
                                                const float* __restrict__ Wk,
                                                const float* __restrict__ Wv,
                                                ushort_t* __restrict__ Wsw) {
  __shared__ float tile[64][65];
  const float* W = (blockIdx.y == 0) ? Wq : (blockIdx.y == 1 ? Wk : Wv);
  int kt = blockIdx.x, t = threadIdx.x;
  int r = t >> 2, cq = t & 3;
  const float* src = W + (kt * 64 + r) * Hh + cq * 16;
#pragma unroll
  for (int j = 0; j < 16; j += 4) {
    float4 v = *reinterpret_cast<const float4*>(src + j);
    tile[r][cq * 16 + j + 0] = v.x;
    tile[r][cq * 16 + j + 1] = v.y;
    tile[r][cq * 16 + j + 2] = v.z;
    tile[r][cq * 16 + j + 3] = v.w;
  }
  __syncthreads();
  int n = t >> 2, kq = t & 3;
  int rr = blockIdx.y * 64 + n;  // W row 0..191
  ushort_t ob[16];
#pragma unroll
  for (int j = 0; j < 16; ++j) ob[j] = f2bfu(tile[kq * 16 + j][n]);
#pragma unroll
  for (int j = 0; j < 2; ++j) {
    int c16 = 2 * kq + j;
    size_t off = ((size_t)(kt * 192 + rr)) * 64 + (size_t)(((c16 ^ (rr & 7))) * 8);
    *reinterpret_cast<uint4*>(Wsw + off) = reinterpret_cast<uint4*>(ob)[j];
  }
}

// ---------------- fused QKV projection (R17 config — best measured) ----------------
__global__ __launch_bounds__(256, 2) void k_proj(const float* __restrict__ hs,
                                                 const float* __restrict__ bq,
                                                 const float* __restrict__ bk,
                                                 const float* __restrict__ bv,
                                                 const ushort_t* __restrict__ Wsw,
                                                 const int* __restrict__ am,
                                                 ushort_t* __restrict__ qf_,
                                                 ushort_t* __restrict__ kf_,
                                                 ushort_t* __restrict__ vf_,
                                                 float* __restrict__ pen) {
  __shared__ __align__(16) ushort_t bufA[2][32][72];      // 9 KB
  __shared__ __align__(16) ushort_t bufW[2][192 * 64];    // 48 KB

  int t = threadIdx.x, w = t >> 6, l = t & 63, g = l >> 4, c = l & 15;
  int wm = w >> 1, wn = w & 1;
  int row0 = blockIdx.x * 32;

  int ar = t >> 3, ach = t & 7;
  const float* agp = hs + (size_t)(row0 + ar) * Ee + ach * 8;

  f32x4 acc[6];
#pragma unroll
  for (int nt = 0; nt < 6; ++nt) acc[nt] = f32x4{0.f, 0.f, 0.f, 0.f};
  float4 aR0, aR1;

  auto LOADA = [&](int kk) {
    aR0 = *reinterpret_cast<const float4*>(agp + kk);
    aR1 = *reinterpret_cast<const float4*>(agp + kk + 4);
  };
  auto WRITEA = [&](int buf) {
    bf16x8 av;
    av[0] = (__bf16)aR0.x; av[1] = (__bf16)aR0.y; av[2] = (__bf16)aR0.z; av[3] = (__bf16)aR0.w;
    av[4] = (__bf16)aR1.x; av[5] = (__bf16)aR1.y; av[6] = (__bf16)aR1.z; av[7] = (__bf16)aR1.w;
    *reinterpret_cast<bf16x8*>(&bufA[buf][ar][ach * 8]) = av;
  };
  auto GLW = [&](int buf, int s) {
    const ushort_t* base = Wsw + (size_t)s * 12288;
#pragma unroll
    for (int j = 0; j < 6; ++j) {
      int seg = j * 4 + w;
      const ushort_t* gp = base + seg * 512 + l * 8;
      gload_lds16(gp, &bufW[buf][seg * 512]);
    }
  };
  auto COMPUTE = [&](int buf) {
    const ushort_t* Ab = &bufA[buf][wm * 16 + c][0];
    bf16x8 af0 = *reinterpret_cast<const bf16x8*>(Ab + g * 8);
    bf16x8 af1 = *reinterpret_cast<const bf16x8*>(Ab + 32 + g * 8);
#pragma unroll
    for (int nt = 0; nt < 6; ++nt) {
      int r = wn * 96 + nt * 16 + c;
      int slot = g ^ (r & 7);
      const ushort_t* Wb = &bufW[buf][r * 64];
      bf16x8 b0 = *reinterpret_cast<const bf16x8*>(Wb + slot * 8);
      bf16x8 b1 = *reinterpret_cast<const bf16x8*>(Wb + (slot ^ 4) * 8);
      acc[nt] = mfma16(af0, b0, acc[nt]);
      acc[nt] = mfma16(af1, b1, acc[nt]);
    }
  };

  LOADA(0);
  WRITEA(0);
  GLW(0, 0);
  LOADA(64);
  __builtin_amdgcn_sched_barrier(0);

  int cur = 0;
  for (int s = 0; s < 16; ++s) {
    __syncthreads();
    if (s < 15) {
      WRITEA(cur ^ 1);
      GLW(cur ^ 1, s + 1);
    }
    if (s < 14) {
      LOADA((s + 2) * 64);
      __builtin_amdgcn_sched_barrier(0);
    }
    COMPUTE(cur);
    cur ^= 1;
  }

#pragma unroll
  for (int nt = 0; nt < 6; ++nt) {
    int T = wn * 6 + nt;
    int m = T >> 2;
    int h = (T & 3) * 16 + c;
    const float* bias = (m == 0) ? bq : ((m == 1) ? bk : bv);
    float bb = bias[h];
    int cc = h >> 4, hh = (h >> 3) & 1, jj = h & 7;
    int dt = h >> 5, dl = h & 31;
#pragma unroll
    for (int i = 0; i < 4; ++i) {
      int row = row0 + wm * 16 + g * 4 + i;
      float val = acc[nt][i] + bb;
      int bi = row >> 11, rl = row & 2047;
      if (m == 0) {
        size_t a = ((((size_t)(bi * 64 + (rl >> 5)) * 4 + cc) * 2 + hh) * 32 + (rl & 31)) * 8 + jj;
        qf_[a] = f2bfu(val * SCLQ);
      } else if (m == 1) {
        size_t a = ((((size_t)(bi * 64 + (rl >> 5)) * 4 + cc) * 2 + hh) * 32 + (rl & 31)) * 8 + jj;
        kf_[a] = f2bfu(val);
      } else {
        int s16 = rl >> 4, vh = (rl >> 3) & 1, vj = rl & 7;
        size_t a = ((((size_t)(bi * 128 + s16) * 2 + dt) * 2 + vh) * 32 + dl) * 8 + vj;
        vf_[a] = f2bfu(val);
      }
    }
  }

  if (t < 32) {
    int grow = row0 + t;
    int bi = grow >> 11, s2 = grow & 2047;
    int mv = am[grow];
    pen[((size_t)bi * 2 + 0) * Ss + s2] = mv ? 0.f : NEG2;
    pen[((size_t)bi * 2 + 1) * Ss + s2] = mv ? NEG2 : 0.f;
  }
}

// ---------------- fused masked flash attention v6: no k-split, in-kernel combine ----
// grid 256: b = bid&7 (batch-per-XCD), qt2 = bid>>3 (64-q double-tile).
// 512 thr / 8 waves; wave w owns keys [w*256, +256) = 8 tiles of 32. Per-wave
// body = R20 (2 q-tiles A/B share K/V fragment regs -> halved L2 traffic, 2x
// ILP). Same 8 waves/CU as R20 (1 block x 8 vs 2 x 4); same 16 MB/XCD L2 load.
// Combine: two-stage LDS reduce (waves 4-7 stash; waves 0-3 add; 512-thr final
// divide) writing DIRECTLY to out — kills k_fin + the 16 MB opart round-trip.
__global__ __launch_bounds__(512, 2) void k_attn(const ushort_t* __restrict__ qs,
                                                 const ushort_t* __restrict__ km,
                                                 const ushort_t* __restrict__ vm,
                                                 const int* __restrict__ am,
                                                 const float* __restrict__ pen,
                                                 float* __restrict__ out) {
  __shared__ float obuf[4][64][68];   // 69.6 KB (static >64KB OK: R7/R8 70656B)
  __shared__ float lls[8][64];        // 2 KB

  int t = threadIdx.x, w = t >> 6, l = t & 63, lo = l & 31, hi = l >> 5;
  int bid = blockIdx.x;
  int b = bid & 7, qt2 = bid >> 3;
  int q0A = qt2 * 64, q0B = q0A + 32;

  const size_t laneoff = (size_t)hi * 256 + lo * 8;

  const ushort_t* qbaseA = qs + (size_t)(b * 64 + qt2 * 2) * 2048 + laneoff;
  const ushort_t* qbaseB = qbaseA + 2048;
  bf16x8 qfA[4], qfB[4];
#pragma unroll
  for (int c = 0; c < 4; ++c) {
    qfA[c] = *reinterpret_cast<const bf16x8*>(qbaseA + (size_t)c * 512);
    qfB[c] = *reinterpret_cast<const bf16x8*>(qbaseB + (size_t)c * 512);
  }

  int mqA = am[b * Ss + q0A + lo], mqB = am[b * Ss + q0B + lo];
  float negqA = mqA ? NEG2 : 0.f, negqB = mqB ? NEG2 : 0.f;
  const float* pselA = pen + ((size_t)b * 2 + (mqA ? 0 : 1)) * Ss;
  const float* pselB = pen + ((size_t)b * 2 + (mqB ? 0 : 1)) * Ss;

  float llA = 0.f, llB = 0.f;
  f32x16 o0A = {0.f, 0.f, 0.f, 0.f, 0.f, 0.f, 0.f, 0.f, 0.f, 0.f, 0.f, 0.f, 0.f, 0.f, 0.f, 0.f};
  f32x16 o1A = o0A, o0B = o0A, o1B = o0A;
  const f32x16 z16 = o0A;

  const int kvbeg = w * 256;
  const ushort_t* kb = km + (size_t)b * 131072 + laneoff;
  const ushort_t* vb = vm + (size_t)b * 131072 + laneoff;

  for (int it = 0; it < 8; ++it) {
    const int kv0 = kvbeg + it * 32;
    const int kt32 = kv0 >> 5, s16 = kv0 >> 4;

    const ushort_t* kfp = kb + (size_t)kt32 * 2048;
    bf16x8 kf0 = *reinterpret_cast<const bf16x8*>(kfp);
    bf16x8 kf1 = *reinterpret_cast<const bf16x8*>(kfp + 512);
    bf16x8 kf2 = *reinterpret_cast<const bf16x8*>(kfp + 1024);
    bf16x8 kf3 = *reinterpret_cast<const bf16x8*>(kfp + 1536);
    const ushort_t* vfp = vb + (size_t)s16 * 1024;
    bf16x8 vf00 = *reinterpret_cast<const bf16x8*>(vfp);
    bf16x8 vf01 = *reinterpret_cast<const bf16x8*>(vfp + 512);
    bf16x8 vf10 = *reinterpret_cast<const bf16x8*>(vfp + 1024);
    bf16x8 vf11 = *reinterpret_cast<const bf16x8*>(vfp + 1536);

    f32x4 pvA[4];
#pragma unroll
    for (int j = 0; j < 4; ++j)
      pvA[j] = *reinterpret_cast<const f32x4*>(pselA + kv0 + j * 8 + hi * 4);

    f32x16 scA = mfma32(kf0, qfA[0], z16);
    scA = mfma32(kf1, qfA[1], scA);
    scA = mfma32(kf2, qfA[2], scA);
    scA = mfma32(kf3, qfA[3], scA);
    f32x16 scB = mfma32(kf0, qfB[0], z16);
    scB = mfma32(kf1, qfB[1], scB);
    scB = mfma32(kf2, qfB[2], scB);
    scB = mfma32(kf3, qfB[3], scB);

    if (kv0 == q0A) {
#pragma unroll
      for (int r = 0; r < 16; ++r) {
        int kr = (r & 3) + 8 * (r >> 2) + 4 * hi;
        scA[r] += pvA[r >> 2][r & 3] + ((kr > lo) ? negqA : 0.f);
      }
    } else {
      float addt = (kv0 > q0A) ? negqA : 0.f;
#pragma unroll
      for (int r = 0; r < 16; ++r) scA[r] += pvA[r >> 2][r & 3] + addt;
    }
    float pA[16], tsA = 0.f;
#pragma unroll
    for (int r = 0; r < 16; ++r) {
      pA[r] = __builtin_amdgcn_exp2f(scA[r]);
      tsA += pA[r];
    }
    llA += tsA;
    unsigned xa0 = cvtpk(pA[0], pA[1]), ya0 = cvtpk(pA[2], pA[3]);
    unsigned za0 = cvtpk(pA[4], pA[5]), wa0 = cvtpk(pA[6], pA[7]);
    swap32(xa0, za0);
    swap32(ya0, wa0);
    unsigned xa1 = cvtpk(pA[8], pA[9]), ya1 = cvtpk(pA[10], pA[11]);
    unsigned za1 = cvtpk(pA[12], pA[13]), wa1 = cvtpk(pA[14], pA[15]);
    swap32(xa1, za1);
    swap32(ya1, wa1);
    bf16x8 paA0 = __builtin_bit_cast(bf16x8, u32x4{xa0, ya0, za0, wa0});
    bf16x8 paA1 = __builtin_bit_cast(bf16x8, u32x4{xa1, ya1, za1, wa1});
    o0A = mfma32(paA0, vf00, o0A);
    o0A = mfma32(paA1, vf10, o0A);
    o1A = mfma32(paA0, vf01, o1A);
    o1A = mfma32(paA1, vf11, o1A);

    f32x4 pvB[4];
#pragma unroll
    for (int j = 0; j < 4; ++j)
      pvB[j] = *reinterpret_cast<const f32x4*>(pselB + kv0 + j * 8 + hi * 4);

    if (kv0 == q0B) {
#pragma unroll
      for (int r = 0; r < 16; ++r) {
        int kr = (r & 3) + 8 * (r >> 2) + 4 * hi;
        scB[r] += pvB[r >> 2][r & 3] + ((kr > lo) ? negqB : 0.f);
      }
    } else {
      float addt = (kv0 > q0B) ? negqB : 0.f;
#pragma unroll
      for (int r = 0; r < 16; ++r) scB[r] += pvB[r >> 2][r & 3] + addt;
    }
    float pB[16], tsB = 0.f;
#pragma unroll
    for (int r = 0; r < 16; ++r) {
      pB[r] = __builtin_amdgcn_exp2f(scB[r]);
      tsB += pB[r];
    }
    llB += tsB;
    unsigned xb0 = cvtpk(pB[0], pB[1]), yb0 = cvtpk(pB[2], pB[3]);
    unsigned zb0 = cvtpk(pB[4], pB[5]), wb0 = cvtpk(pB[6], pB[7]);
    swap32(xb0, zb0);
    swap32(yb0, wb0);
    unsigned xb1 = cvtpk(pB[8], pB[9]), yb1 = cvtpk(pB[10], pB[11]);
    unsigned zb1 = cvtpk(pB[12], pB[13]), wb1 = cvtpk(pB[14], pB[15]);
    swap32(xb1, zb1);
    swap32(yb1, wb1);
    bf16x8 paB0 = __builtin_bit_cast(bf16x8, u32x4{xb0, yb0, zb0, wb0});
    bf16x8 paB1 = __builtin_bit_cast(bf16x8, u32x4{xb1, yb1, zb1, wb1});
    o0B = mfma32(paB0, vf00, o0B);
    o0B = mfma32(paB1, vf10, o0B);
    o1B = mfma32(paB0, vf01, o1B);
    o1B = mfma32(paB1, vf11, o1B);
  }

  llA += __shfl_xor(llA, 32);
  llB += __shfl_xor(llB, 32);
  if (hi == 0) {
    lls[w][lo] = llA;
    lls[w][32 + lo] = llB;
  }

  // ---- stage 1: waves 4-7 stash partials ----
  if (w >= 4) {
#pragma unroll
    for (int r = 0; r < 16; ++r) {
      int qrow = (r & 3) + 8 * (r >> 2) + 4 * hi;
      obuf[w - 4][qrow][lo] = o0A[r];
      obuf[w - 4][qrow][32 + lo] = o1A[r];
      obuf[w - 4][32 + qrow][lo] = o0B[r];
      obuf[w - 4][32 + qrow][32 + lo] = o1B[r];
    }
  }
  __syncthreads();
  // ---- stage 2: waves 0-3 add their partials into the stash ----
  if (w < 4) {
#pragma unroll
    for (int r = 0; r < 16; ++r) {
      int qrow = (r & 3) + 8 * (r >> 2) + 4 * hi;
      obuf[w][qrow][lo] += o0A[r];
      obuf[w][qrow][32 + lo] += o1A[r];
      obuf[w][32 + qrow][lo] += o0B[r];
      obuf[w][32 + qrow][32 + lo] += o1B[r];
    }
  }
  __syncthreads();

  // ---- final: 512 threads, row = t>>3 (0..63), dg = t&7; divide, write out ----
  int qr = t >> 3, dg = t & 7;
  float lg = 0.f;
#pragma unroll
  for (int ww = 0; ww < 8; ++ww) lg += lls[ww][qr];
  float a8[8] = {0.f, 0.f, 0.f, 0.f, 0.f, 0.f, 0.f, 0.f};
#pragma unroll
  for (int ww = 0; ww < 4; ++ww) {
    float4 c0 = *reinterpret_cast<const float4*>(&obuf[ww][qr][dg * 8]);
    float4 c1 = *reinterpret_cast<const float4*>(&obuf[ww][qr][dg * 8 + 4]);
    a8[0] += c0.x; a8[1] += c0.y; a8[2] += c0.z; a8[3] += c0.w;
    a8[4] += c1.x; a8[5] += c1.y; a8[6] += c1.z; a8[7] += c1.w;
  }
  float inv = 1.f / lg;
  float4 r0v = {a8[0] * inv, a8[1] * inv, a8[2] * inv, a8[3] * inv};
  float4 r1v = {a8[4] * inv, a8[5] * inv, a8[6] * inv, a8[7] * inv};
  float* op = out + ((size_t)(b * Ss + q0A + qr)) * Hh + dg * 8;
  *reinterpret_cast<float4*>(op) = r0v;
  *reinterpret_cast<float4*>(op + 4) = r1v;
}

extern "C" void kernel_launch(void* const* d_in, const int* in_sizes, int n_in,
                              void* d_out, int out_size, void* d_ws, size_t ws_size,
                              hipStream_t stream) {
  const float* hs = (const float*)d_in[0];
  const int* am = (const int*)d_in[1];
  const float* Wq = (const float*)d_in[2];
  const float* bq = (const float*)d_in[3];
  const float* Wk = (const float*)d_in[4];
  const float* bk = (const float*)d_in[5];
  const float* Wv = (const float*)d_in[6];
  const float* bv = (const float*)d_in[7];
  float* out = (float*)d_out;

  char* ws = (char*)d_ws;
  ushort_t* qsp = (ushort_t*)(ws + 0);                  // 2 MB: Q fragment-major, scaled
  ushort_t* kp = (ushort_t*)(ws + (2u << 20));          // 2 MB: K fragment-major
  ushort_t* vtp = (ushort_t*)(ws + (4u << 20));         // 2 MB: V fragment-major
  ushort_t* wtp = (ushort_t*)(ws + (6u << 20));         // 384 KB: Wsw pre-swizzled
  float* penp = (float*)(ws + (6u << 20) + (512u << 10));  // 128 KB: [B][2][S] f32

  k_wtrans<<<dim3(16, 3), 256, 0, stream>>>(Wq, Wk, Wv, wtp);
  k_proj<<<dim3(512), 256, 0, stream>>>(hs, bq, bk, bv, wtp, am, qsp, kp, vtp, penp);
  k_attn<<<dim3(256), 512, 0, stream>>>(qsp, kp, vtp, am, penp, out);
}